// Round 1
// baseline (523.262 us; speedup 1.0000x reference)
//
#include <hip/hip_runtime.h>

#define BATCH 8
#define PTS 32768
#define FEAT 256
#define FD 16
#define BP (PTS*FEAT)            // 8388608 elements per batch of x
#define QKSZ (FD*PTS)            // 524288
#define Q_OFF ((size_t)0)
#define K_OFF ((size_t)4194304)
#define P_OFF ((size_t)8388608)
#define E_OFF ((size_t)8404992)
#define ATT_OFF ((size_t)67108864)

typedef __attribute__((ext_vector_type(8))) short short8;
typedef __attribute__((ext_vector_type(4))) float f32x4;

__device__ __forceinline__ unsigned short f2bf(float f){
  unsigned u = __float_as_uint(f);
  u += 0x7FFFu + ((u>>16)&1u);
  return (unsigned short)(u>>16);
}

// ---------------- K1: q,k = W{q,k} @ x1 + b  (x1[b,c,p] = xflat[b*BP + c*PTS + p])
__global__ void __launch_bounds__(256) k_qk(const float* __restrict__ x,
    const float* __restrict__ Wq, const float* __restrict__ bq,
    const float* __restrict__ Wk, const float* __restrict__ bk,
    float* __restrict__ scr){
  __shared__ float wlds[256][36];   // [c][0..15]=Wq[o][c], [16..31]=Wk[o][c]; pad->36 (16B align rows)
  int t = threadIdx.x;
  int b = blockIdx.y;
  int p = blockIdx.x*256 + t;
  for (int idx = t; idx < 4096; idx += 256){
    int o = idx>>8, c = idx&255;
    wlds[c][o]    = Wq[idx];
    wlds[c][16+o] = Wk[idx];
  }
  __syncthreads();
  const float* xb = x + (size_t)b*BP;
  float qa[16], ka[16];
  #pragma unroll
  for (int o=0;o<16;o++){ qa[o]=0.f; ka[o]=0.f; }
  for (int c=0;c<256;c++){
    float xv = xb[(size_t)c*PTS + p];
    const float4* wrow = (const float4*)(&wlds[c][0]);
    #pragma unroll
    for (int i=0;i<4;i++){
      float4 wq = wrow[i], wk = wrow[4+i];
      qa[4*i+0] += wq.x*xv; qa[4*i+1] += wq.y*xv; qa[4*i+2] += wq.z*xv; qa[4*i+3] += wq.w*xv;
      ka[4*i+0] += wk.x*xv; ka[4*i+1] += wk.y*xv; ka[4*i+2] += wk.z*xv; ka[4*i+3] += wk.w*xv;
    }
  }
  size_t qb = (size_t)b*QKSZ;
  #pragma unroll
  for (int o=0;o<16;o++){
    scr[Q_OFF + qb + (size_t)o*PTS + p] = qa[o] + bq[o];
    scr[K_OFF + qb + (size_t)o*PTS + p] = ka[o] + bk[o];
  }
}

// ---------------- K2: partial energy.  energy[b,f,g] = sum_{idx & 15 == g} q[b,f,idx>>4]*kflat[b,idx]
__global__ void __launch_bounds__(256) k_energy(float* __restrict__ scr){
  int t = threadIdx.x;
  int ch = blockIdx.x, f = blockIdx.y, b = blockIdx.z;
  const float* qb = scr + Q_OFF + (size_t)b*QKSZ + (size_t)f*PTS;
  const float* kb = scr + K_OFF + (size_t)b*QKSZ;
  float acc = 0.f;
  int base = ch*65536;
  for (int ii=0; ii<256; ii++){
    int idx = base + ii*256 + t;      // idx&15 == t&15 always
    acc += kb[idx]*qb[idx>>4];
  }
  __shared__ float red[256];
  red[t] = acc;
  __syncthreads();
  if (t < 16){
    float s = 0.f;
    #pragma unroll
    for (int j=0;j<16;j++) s += red[t + 16*j];
    scr[P_OFF + (size_t)ch*2048 + ((size_t)b*16 + (size_t)f)*16 + t] = s;
  }
}

__global__ void __launch_bounds__(256) k_ereduce(float* __restrict__ scr){
  int e = blockIdx.x*256 + threadIdx.x;
  float s = 0.f;
  #pragma unroll
  for (int ch=0; ch<8; ch++) s += scr[P_OFF + (size_t)ch*2048 + e];
  scr[E_OFF + e] = s;
}

// ---------------- K3: attention = softmax_r( bup + [r%16<3 && c%16<3] * Wup[r%16,c%16]*energy[b,r>>4,c>>4] )
__global__ void __launch_bounds__(256) k_softmax(float* __restrict__ scr,
    const float* __restrict__ Wup, const float* __restrict__ bup){
  __shared__ float el[256];          // energy[b][f][g] at f*16+g
  int b = blockIdx.x, t = threadIdx.x;
  el[t] = scr[E_OFF + (size_t)b*256 + t];
  __syncthreads();
  int ec = t>>4, kw = t&15;          // thread = column c = t
  float bupv = bup[0];
  bool sp = (kw < 3);
  float w0=0.f,w1=0.f,w2=0.f;
  if (sp){ w0 = Wup[kw]; w1 = Wup[3+kw]; w2 = Wup[6+kw]; }
  float m = bupv;
  float sum;
  if (sp){
    #pragma unroll
    for (int rh=0; rh<16; rh++){
      float e = el[rh*16+ec];
      m = fmaxf(m, fmaxf(fmaxf(w0*e, w1*e), w2*e) + bupv);
    }
    sum = 208.f*__expf(bupv - m);
    for (int rh=0; rh<16; rh++){
      float e = el[rh*16+ec];
      sum += __expf(bupv + w0*e - m) + __expf(bupv + w1*e - m) + __expf(bupv + w2*e - m);
    }
  } else {
    sum = 256.f;                     // m = bupv, all entries equal
  }
  float inv = 1.f/sum;
  float* attp = scr + ATT_OFF + (size_t)b*65536;
  for (int r=0; r<256; r++){
    int kh = r&15;
    float v;
    if (sp && kh < 3){
      float e = el[(r>>4)*16 + ec];
      float w = (kh==0)? w0 : ((kh==1)? w1 : w2);
      v = __expf(bupv + w*e - m)*inv;
    } else {
      v = __expf(bupv - m)*inv;
    }
    attp[(size_t)r*256 + t] = v;
  }
}

// ---------------- K4a: v = Wv @ x1 + bv  -> stored f32 into d_out (natural [b][o][pp] layout)
__global__ void __launch_bounds__(256) k_vgemm(const float* __restrict__ x,
    const float* __restrict__ Wv, const float* __restrict__ bv,
    float* __restrict__ outb){
  __shared__ short At[128][40];      // A[m][k] bf16, rows padded to 40 shorts (80B, 16B-aligned)
  __shared__ short Bt[128][40];      // B^T: [n][k]
  int t = threadIdx.x;
  int mt = blockIdx.x, nt = blockIdx.y, b = blockIdx.z;
  const float* xb = x + (size_t)b*BP + (size_t)nt*128;
  const float* Av = Wv + (size_t)mt*128*256;
  int w = t>>6, l = t&63;
  int wr = w>>1, wc = w&1;
  f32x4 acc[4][4] = {};
  int am = t>>1, akq = (t&1)*16;
  int bcl = (t>>4)*2, bn8 = (t&15)*8;

  for (int kk=0; kk<8; kk++){
    int c0 = kk*32;
    { // stage A: Wv[mt*128 + m][c0..c0+32)
      const float* s = Av + (size_t)am*256 + c0 + akq;
      float4 v0 = ((const float4*)s)[0];
      float4 v1 = ((const float4*)s)[1];
      float4 v2 = ((const float4*)s)[2];
      float4 v3 = ((const float4*)s)[3];
      short8 h0, h1;
      h0[0]=f2bf(v0.x); h0[1]=f2bf(v0.y); h0[2]=f2bf(v0.z); h0[3]=f2bf(v0.w);
      h0[4]=f2bf(v1.x); h0[5]=f2bf(v1.y); h0[6]=f2bf(v1.z); h0[7]=f2bf(v1.w);
      h1[0]=f2bf(v2.x); h1[1]=f2bf(v2.y); h1[2]=f2bf(v2.z); h1[3]=f2bf(v2.w);
      h1[4]=f2bf(v3.x); h1[5]=f2bf(v3.y); h1[6]=f2bf(v3.z); h1[7]=f2bf(v3.w);
      *(short8*)&At[am][akq]   = h0;
      *(short8*)&At[am][akq+8] = h1;
    }
    { // stage B transposed: x1 rows c0+bcl, c0+bcl+1, cols bn8..bn8+8
      const float* s0 = xb + (size_t)(c0+bcl)*PTS + bn8;
      const float* s1 = s0 + PTS;
      float4 a0 = ((const float4*)s0)[0];
      float4 a1 = ((const float4*)s0)[1];
      float4 b0 = ((const float4*)s1)[0];
      float4 b1 = ((const float4*)s1)[1];
      float r0[8] = {a0.x,a0.y,a0.z,a0.w,a1.x,a1.y,a1.z,a1.w};
      float r1[8] = {b0.x,b0.y,b0.z,b0.w,b1.x,b1.y,b1.z,b1.w};
      #pragma unroll
      for (int j=0;j<8;j++){
        unsigned pk = (unsigned)f2bf(r0[j]) | ((unsigned)f2bf(r1[j])<<16);
        *(unsigned*)&Bt[bn8+j][bcl] = pk;
      }
    }
    __syncthreads();
    short8 af[4], bfv[4];
    #pragma unroll
    for (int mi=0;mi<4;mi++) af[mi]  = *(const short8*)&At[64*wr+16*mi+(l&15)][(l>>4)*8];
    #pragma unroll
    for (int ni=0;ni<4;ni++) bfv[ni] = *(const short8*)&Bt[64*wc+16*ni+(l&15)][(l>>4)*8];
    #pragma unroll
    for (int mi=0;mi<4;mi++){
      #pragma unroll
      for (int ni=0;ni<4;ni++)
        acc[mi][ni] = __builtin_amdgcn_mfma_f32_16x16x32_bf16(af[mi], bfv[ni], acc[mi][ni], 0, 0, 0);
    }
    __syncthreads();
  }
  float* ob = outb + (size_t)b*BP;
  #pragma unroll
  for (int mi=0;mi<4;mi++){
    int rbase = mt*128 + 64*wr + 16*mi + ((l>>4)<<2);
    float bvv[4];
    #pragma unroll
    for (int j=0;j<4;j++) bvv[j] = bv[rbase+j];
    #pragma unroll
    for (int ni=0;ni<4;ni++){
      int col = nt*128 + 64*wc + 16*ni + (l&15);
      #pragma unroll
      for (int j=0;j<4;j++)
        ob[(size_t)(rbase+j)*PTS + col] = acc[mi][ni][j] + bvv[j];
    }
  }
}

// ---------------- K4b: out rows {128P+r} = gamma*(V_tile @ att) + x rows, fully in place on d_out.
// V_tile(b,r)[P,f] = v[b,P,256r+f] lives at the SAME flat addresses as the out rows this block writes.
__global__ void __launch_bounds__(256) k_outgemm(const float* __restrict__ x,
    const float* __restrict__ gma, float* __restrict__ outb){
  __shared__ short Vl[64][264];      // V rows (bf16), padded to 264 shorts (528B, 16B-aligned)
  __shared__ short Atl[32][264];     // att^T tile: [g_local][f]
  int t = threadIdx.x;
  int Pq = blockIdx.x, r = blockIdx.y, b = blockIdx.z;
  const float* vsrc = outb + (size_t)b*BP + (size_t)Pq*64*PTS + (size_t)r*256;
  #pragma unroll
  for (int i=0;i<8;i++){             // stage V: 64 rows x 256 f
    int row = (t>>5) + 8*i;
    int col = (t&31)*8;
    const float* s = vsrc + (size_t)row*PTS + col;
    float4 v0 = ((const float4*)s)[0];
    float4 v1 = ((const float4*)s)[1];
    short8 h;
    h[0]=f2bf(v0.x); h[1]=f2bf(v0.y); h[2]=f2bf(v0.z); h[3]=f2bf(v0.w);
    h[4]=f2bf(v1.x); h[5]=f2bf(v1.y); h[6]=f2bf(v1.z); h[7]=f2bf(v1.w);
    *(short8*)&Vl[row][col] = h;
  }
  float gm = gma[0];
  const float* attb = outb + ATT_OFF + (size_t)b*65536;
  const float* xb = x + (size_t)b*BP + (size_t)Pq*64*PTS + (size_t)r*256;
  float* ob = outb + (size_t)b*BP + (size_t)Pq*64*PTS + (size_t)r*256;
  int w = t>>6, l = t&63;
  int wr = w>>1, wc = w&1;
  for (int gt=0; gt<8; gt++){
    int g0 = gt*32;
    __syncthreads();                 // Atl reuse guard (also orders V writes before first use)
    {                                // stage att^T tile: thread t = row f
      const float* s = attb + (size_t)t*256 + g0;
      #pragma unroll
      for (int j=0;j<8;j++){
        float4 av = ((const float4*)s)[j];
        Atl[4*j+0][t] = (short)f2bf(av.x);
        Atl[4*j+1][t] = (short)f2bf(av.y);
        Atl[4*j+2][t] = (short)f2bf(av.z);
        Atl[4*j+3][t] = (short)f2bf(av.w);
      }
    }
    __syncthreads();
    f32x4 acc[2] = {};
    #pragma unroll
    for (int ks=0; ks<8; ks++){
      short8 bfrag = *(const short8*)&Atl[16*wc + (l&15)][ks*32 + ((l>>4)<<3)];
      #pragma unroll
      for (int mi=0;mi<2;mi++){
        short8 afrag = *(const short8*)&Vl[32*wr + 16*mi + (l&15)][ks*32 + ((l>>4)<<3)];
        acc[mi] = __builtin_amdgcn_mfma_f32_16x16x32_bf16(afrag, bfrag, acc[mi], 0, 0, 0);
      }
    }
    #pragma unroll
    for (int mi=0;mi<2;mi++){
      int Pl = 32*wr + 16*mi + ((l>>4)<<2);
      int g = g0 + 16*wc + (l&15);
      #pragma unroll
      for (int j=0;j<4;j++){
        size_t a = (size_t)(Pl+j)*PTS + g;
        ob[a] = gm*acc[mi][j] + xb[a];
      }
    }
  }
}

extern "C" void kernel_launch(void* const* d_in, const int* in_sizes, int n_in,
                              void* d_out, int out_size, void* d_ws, size_t ws_size,
                              hipStream_t stream) {
  const float* x   = (const float*)d_in[0];
  const float* Wq  = (const float*)d_in[1];
  const float* bq  = (const float*)d_in[2];
  const float* Wk  = (const float*)d_in[3];
  const float* bk  = (const float*)d_in[4];
  const float* Wv  = (const float*)d_in[5];
  const float* bv  = (const float*)d_in[6];
  const float* Wup = (const float*)d_in[7];
  const float* bup = (const float*)d_in[8];
  const float* gma = (const float*)d_in[9];
  float* out = (float*)d_out;

  k_qk     <<<dim3(128,8),   256, 0, stream>>>(x, Wq, bq, Wk, bk, out);
  k_energy <<<dim3(8,16,8),  256, 0, stream>>>(out);
  k_ereduce<<<dim3(8),       256, 0, stream>>>(out);
  k_softmax<<<dim3(8),       256, 0, stream>>>(out, Wup, bup);
  k_vgemm  <<<dim3(2,256,8), 256, 0, stream>>>(x, Wv, bv, out);
  k_outgemm<<<dim3(4,128,8), 256, 0, stream>>>(x, gma, out);
}